// Round 2
// baseline (820.131 us; speedup 1.0000x reference)
//
#include <hip/hip_runtime.h>

// EMD via Sinkhorn on 64 Hamming states, eps=0.1.
// K = exp(-C/eps) = tensor product of six 2x2 [[1,a],[a,1]], a = exp(-10)
//   => K-apply is 6 butterfly stages (384 FMA), not a 64x64 matvec.
// Scale invariance: the Sinkhorn map u -> p/(K(q/(Ku))) is 1-homogeneous, so
// we iterate on RAW p,q (no +TINY, no /sum): all normalizations collapse to
// per-iteration global scalars that cancel in the output ratios. The single
// surviving factor 1/sum(p) is applied once in the epilogue.
// EMD readout (w = K v_final, u = p/w):
//   emd = (a * sum_b u.X_b w) / ((1-a^2) * sum(p)) - 6a^2/(1-a^2)
// One thread per batch row; only w[64] stays resident (p,q re-loaded from
// global each half-step -- loop-invariant addresses, L2-resident data).

namespace {

constexpr int   N     = 64;
constexpr int   NBITS = 6;
constexpr int   ITERS = 50;

constexpr double Ad = 4.5399929762484854e-05;           // exp(-10)
constexpr float  A  = (float)Ad;
constexpr float  EMD_SCALE = (float)(Ad / (1.0 - Ad * Ad));
constexpr float  EMD_DIAG  = (float)(6.0 * Ad * Ad / (1.0 - Ad * Ad));

__device__ __forceinline__ float rcp(float x) { return __builtin_amdgcn_rcpf(x); }

// In-place w <- K w (K symmetric; serves both u@K and v@K^T).
__device__ __forceinline__ void butterfly(float w[N]) {
#pragma unroll
  for (int b = 0; b < NBITS; ++b) {
#pragma unroll
    for (int i = 0; i < N; ++i) {
      if ((i & (1 << b)) == 0) {
        const int j = i | (1 << b);
        const float wi = w[i];
        const float wj = w[j];
        w[i] = fmaf(A, wj, wi);
        w[j] = fmaf(A, wi, wj);
      }
    }
  }
}

__global__ __launch_bounds__(256, 4) void emd_sinkhorn_kernel(
    const float* __restrict__ gp, const float* __restrict__ gq,
    float* __restrict__ out, int nbatch) {
  const int b = blockIdx.x * 256 + threadIdx.x;
  if (b >= nbatch) return;

  const float4* __restrict__ p4 =
      reinterpret_cast<const float4*>(gp) + (size_t)b * (N / 4);
  const float4* __restrict__ q4 =
      reinterpret_cast<const float4*>(gq) + (size_t)b * (N / 4);

  float w[N];

  // u0 = ones => K u0 = (1+a)^6 * ones => v1 propto q. Global scale drops out.
#pragma unroll
  for (int k = 0; k < N / 4; ++k) {
    const float4 t = q4[k];
    w[4 * k + 0] = t.x;
    w[4 * k + 1] = t.y;
    w[4 * k + 2] = t.z;
    w[4 * k + 3] = t.w;
  }

  // 49 full iterations: u_k = p/(K v_k); v_{k+1} = q/(K u_k)  (up to scalars).
#pragma unroll 1
  for (int it = 0; it < ITERS - 1; ++it) {
    butterfly(w);  // K v_k
#pragma unroll
    for (int k = 0; k < N / 4; ++k) {
      const float4 t = p4[k];  // loop-invariant address; hoistable load
      w[4 * k + 0] = t.x * rcp(w[4 * k + 0]);
      w[4 * k + 1] = t.y * rcp(w[4 * k + 1]);
      w[4 * k + 2] = t.z * rcp(w[4 * k + 2]);
      w[4 * k + 3] = t.w * rcp(w[4 * k + 3]);
    }
    butterfly(w);  // K u_k
#pragma unroll
    for (int k = 0; k < N / 4; ++k) {
      const float4 t = q4[k];
      w[4 * k + 0] = t.x * rcp(w[4 * k + 0]);
      w[4 * k + 1] = t.y * rcp(w[4 * k + 1]);
      w[4 * k + 2] = t.z * rcp(w[4 * k + 2]);
      w[4 * k + 3] = t.w * rcp(w[4 * k + 3]);
    }
  }

  // w = K v_50 ; u_50 = p/w formed on the fly in the readout.
  butterfly(w);

  float sp = 0.f;  // sum(p) -- the only surviving normalization factor
  float sx = 0.f;  // sum_i u_i * sum_b w[i^b]
#pragma unroll
  for (int k = 0; k < N / 4; ++k) {
    const float4 t = p4[k];
    const float pv[4] = {t.x, t.y, t.z, t.w};
#pragma unroll
    for (int j = 0; j < 4; ++j) {
      const int i = 4 * k + j;
      sp += pv[j];
      const float ui = pv[j] * rcp(w[i]);
      float nb = w[i ^ 1];
#pragma unroll
      for (int bb = 1; bb < NBITS; ++bb) nb += w[i ^ (1 << bb)];
      sx = fmaf(ui, nb, sx);
    }
  }

  out[b] = fmaf(sx * rcp(sp), EMD_SCALE, -EMD_DIAG);
}

}  // namespace

extern "C" void kernel_launch(void* const* d_in, const int* in_sizes, int n_in,
                              void* d_out, int out_size, void* d_ws, size_t ws_size,
                              hipStream_t stream) {
  const float* p = (const float*)d_in[0];
  const float* q = (const float*)d_in[1];
  // d_in[2] is the Hamming cost matrix; its tensor-product structure is
  // hardcoded (a = exp(-1/eps) = exp(-10)).
  float* out = (float*)d_out;

  const int nbatch = in_sizes[0] / N;  // 262144
  const int block = 256;
  const int grid = (nbatch + block - 1) / block;
  emd_sinkhorn_kernel<<<grid, block, 0, stream>>>(p, q, out, nbatch);
}

// Round 3
// 493.762 us; speedup vs baseline: 1.6610x; 1.6610x over previous
//
#include <hip/hip_runtime.h>

// EMD via Sinkhorn on 64 Hamming states, eps=0.1.
// K = exp(-C/eps) = tensor product of six 2x2 [[1,a],[a,1]], a = exp(-10)
//   => K-apply is 6 butterfly stages (384 FMA), not a 64x64 matvec.
// Scale invariance: the Sinkhorn map u -> p/(K(q/(Ku))) is 1-homogeneous, so
// we iterate on RAW p,q (no +TINY, no /sum); all normalizations collapse to
// per-iteration scalars that cancel in the output ratios. The single
// surviving factor 1/sum(p) is applied once in the epilogue.
// EMD readout (w = K v_final, u = p/w):
//   emd = (a * sum_b u.X_b w) / ((1-a^2) * sum(p)) - 6a^2/(1-a^2)
//
// R2 post-mortem: the compiler REMATERIALIZES global loads of p,q each
// half-step instead of keeping them in VGPRs (FETCH 69MB -> 2.2GB, kernel
// went memory-latency-bound). Fix: pin every loaded element with an empty
// asm "+v" constraint -- the value becomes opaque, remat is impossible, and
// the allocator keeps all 192 floats resident (fits the 256-VGPR budget of
// __launch_bounds__(256,2); 2 waves/SIMD is plenty for a 32-way-ILP VALU
// kernel -- R1 held 96% VALUBusy at the same occupancy).

namespace {

constexpr int   N     = 64;
constexpr int   NBITS = 6;
constexpr int   ITERS = 50;

constexpr double Ad = 4.5399929762484854e-05;           // exp(-10)
constexpr float  A  = (float)Ad;
constexpr float  EMD_SCALE = (float)(Ad / (1.0 - Ad * Ad));
constexpr float  EMD_DIAG  = (float)(6.0 * Ad * Ad / (1.0 - Ad * Ad));

__device__ __forceinline__ float rcp(float x) { return __builtin_amdgcn_rcpf(x); }

// In-place w <- K w (K symmetric; serves both u@K and v@K^T).
__device__ __forceinline__ void butterfly(float w[N]) {
#pragma unroll
  for (int b = 0; b < NBITS; ++b) {
#pragma unroll
    for (int i = 0; i < N; ++i) {
      if ((i & (1 << b)) == 0) {
        const int j = i | (1 << b);
        const float wi = w[i];
        const float wj = w[j];
        w[i] = fmaf(A, wj, wi);
        w[j] = fmaf(A, wi, wj);
      }
    }
  }
}

__global__ __launch_bounds__(256, 2) void emd_sinkhorn_kernel(
    const float* __restrict__ gp, const float* __restrict__ gq,
    float* __restrict__ out, int nbatch) {
  const int b = blockIdx.x * 256 + threadIdx.x;
  if (b >= nbatch) return;

  const float4* __restrict__ p4 =
      reinterpret_cast<const float4*>(gp) + (size_t)b * (N / 4);
  const float4* __restrict__ q4 =
      reinterpret_cast<const float4*>(gq) + (size_t)b * (N / 4);

  float p[N], q[N], w[N];

  // Load p,q ONCE.
#pragma unroll
  for (int k = 0; k < N / 4; ++k) {
    const float4 tp = p4[k];
    p[4 * k + 0] = tp.x;
    p[4 * k + 1] = tp.y;
    p[4 * k + 2] = tp.z;
    p[4 * k + 3] = tp.w;
    const float4 tq = q4[k];
    q[4 * k + 0] = tq.x;
    q[4 * k + 1] = tq.y;
    q[4 * k + 2] = tq.z;
    q[4 * k + 3] = tq.w;
  }
  // Pin every element in a VGPR: value becomes opaque to the compiler, so it
  // cannot rematerialize the global load inside the iteration loop.
#pragma unroll
  for (int i = 0; i < N; ++i) {
    asm volatile("" : "+v"(p[i]));
    asm volatile("" : "+v"(q[i]));
  }

  // u0 = ones => K u0 propto ones => v1 propto q (scale drops out).
#pragma unroll
  for (int i = 0; i < N; ++i) w[i] = q[i];

  // 49 full iterations: u_k = p/(K v_k); v_{k+1} = q/(K u_k)  (up to scalars).
#pragma unroll 1
  for (int it = 0; it < ITERS - 1; ++it) {
    butterfly(w);  // K v_k
#pragma unroll
    for (int i = 0; i < N; ++i) w[i] = p[i] * rcp(w[i]);  // u_k
    butterfly(w);  // K u_k
#pragma unroll
    for (int i = 0; i < N; ++i) w[i] = q[i] * rcp(w[i]);  // v_{k+1}
  }

  // w = K v_50 ; u_50 = p/w formed on the fly in the readout.
  butterfly(w);

  float sp = 0.f;  // sum(p) -- the only surviving normalization factor
  float sx = 0.f;  // sum_i u_i * sum_b w[i^b]
#pragma unroll
  for (int i = 0; i < N; ++i) {
    sp += p[i];
    const float ui = p[i] * rcp(w[i]);
    float nb = w[i ^ 1];
#pragma unroll
    for (int bb = 1; bb < NBITS; ++bb) nb += w[i ^ (1 << bb)];
    sx = fmaf(ui, nb, sx);
  }

  out[b] = fmaf(sx * rcp(sp), EMD_SCALE, -EMD_DIAG);
}

}  // namespace

extern "C" void kernel_launch(void* const* d_in, const int* in_sizes, int n_in,
                              void* d_out, int out_size, void* d_ws, size_t ws_size,
                              hipStream_t stream) {
  const float* p = (const float*)d_in[0];
  const float* q = (const float*)d_in[1];
  // d_in[2] is the Hamming cost matrix; its tensor-product structure is
  // hardcoded (a = exp(-1/eps) = exp(-10)).
  float* out = (float*)d_out;

  const int nbatch = in_sizes[0] / N;  // 262144
  const int block = 256;
  const int grid = (nbatch + block - 1) / block;
  emd_sinkhorn_kernel<<<grid, block, 0, stream>>>(p, q, out, nbatch);
}